// Round 5
// baseline (241.925 us; speedup 1.0000x reference)
//
#include <hip/hip_runtime.h>
#include <hip/hip_fp16.h>

#define S_LEN    1024
#define B_SZ     8
#define D_IN     64
#define D_OUT    96
#define NB       8
#define NE       (D_OUT * D_OUT)     // 9216 elements per layer
#define CHUNK    8                   // s-steps per recurrence chain
#define NCHUNK   (S_LEN / CHUNK)     // 128 -> 4608 blocks = 18/CU exactly
#define SPAD     100                 // padded row stride (floats), 96-wide rows
#define XPAD     68                  // padded row stride (floats), 64-wide rows
#define HPAD     104                 // padded row stride (halves) for W tile
#define NT_MAIN  512                 // 8 waves/block, 2 blocks/CU -> 32 waves/CU
#define NT_W     256

__device__ __forceinline__ float cos_rev(float v) {   // cos(2*pi*v), v in revolutions
    v -= floorf(v);
    return __builtin_amdgcn_cosf(v);
}

// ---------------- Kernel 1: materialize W1, W2 (f16) for all s ----------------
// c(s+1) = 2cos(2pi/p)*c(s) - c(s-1). One thread owns one element e (8 chains).
__global__ void __launch_bounds__(NT_W)
w_kernel(const float* __restrict__ P1, const float* __restrict__ P2,
         __half* __restrict__ W1, __half* __restrict__ W2) {
    const int c  = blockIdx.x / (NE / NT_W);
    const int eb = blockIdx.x % (NE / NT_W);
    const int e  = eb * NT_W + threadIdx.x;
    const int s0 = c * CHUNK;
    const float s0f = (float)s0;

    float p1l[NB], p2l[NB];
    *(float4*)&p1l[0] = *(const float4*)(P1 + e * NB);
    *(float4*)&p1l[4] = *(const float4*)(P1 + e * NB + 4);
    *(float4*)&p2l[0] = *(const float4*)(P2 + e * NB);
    *(float4*)&p2l[4] = *(const float4*)(P2 + e * NB + 4);

    float cc[NB], cp[NB], kk[NB];
    #pragma unroll
    for (int g = 0; g < NB; ++g) {
        const float inv = __builtin_amdgcn_rcpf((float)(e * NB + 2 + g));
        cc[g] = cos_rev(s0f * inv);            // c(s0)
        cp[g] = cos_rev((s0f - 1.0f) * inv);   // c(s0-1); cos even, s0=0 fine
        kk[g] = 2.0f * __builtin_amdgcn_cosf(inv);  // 2cos(2pi/p), inv <= 0.5
    }

    #pragma unroll
    for (int s = s0; s < s0 + CHUNK; ++s) {
        float a1 = 0.0f, a2 = 0.0f;
        #pragma unroll
        for (int g = 0; g < NB; ++g) {
            a1 = fmaf(p1l[g], cc[g], a1);
            a2 = fmaf(p2l[g], cc[g], a2);
        }
        W1[s * NE + e] = __float2half(a1);   // lanes consecutive e -> coalesced
        W2[s * NE + e] = __float2half(a2);
        #pragma unroll
        for (int g = 0; g < NB; ++g) {
            float cn = fmaf(kk[g], cc[g], -cp[g]);
            cp[g] = cc[g];
            cc[g] = cn;
        }
    }
}

// ---------------- helpers for the 512-thread main kernel ----------------
// LayerNorm, one wave64 per batch row (8 waves = 8 rows).
__device__ __forceinline__ void block_layernorm_w64(float* __restrict__ buf,
                                                    const float* __restrict__ gamma,
                                                    const float* __restrict__ beta,
                                                    int tid) {
    const int b    = tid >> 6;
    const int lane = tid & 63;
    float* row = buf + b * SPAD;
    const bool hi = (lane < 32);
    float v0 = row[lane];
    float v1 = hi ? row[lane + 64] : 0.0f;
    float sum = v0 + v1;
    float sq  = fmaf(v0, v0, v1 * v1);
    #pragma unroll
    for (int off = 32; off > 0; off >>= 1) {
        sum += __shfl_down(sum, off, 64);
        sq  += __shfl_down(sq,  off, 64);
    }
    sum = __shfl(sum, 0, 64);
    sq  = __shfl(sq,  0, 64);
    const float mu  = sum * (1.0f / 96.0f);
    const float var = fmaf(sq, 1.0f / 96.0f, -(mu * mu));
    const float rs  = rsqrtf(var + 1e-5f);
    row[lane] = fmaf((v0 - mu) * rs, gamma[lane], beta[lane]);
    if (hi)
        row[lane + 64] = fmaf((v1 - mu) * rs, gamma[lane + 64], beta[lane + 64]);
}

// acc = sum_j xr[j] * wrow[j], W f16 in LDS. Two 6-chunk halves to keep
// in-flight registers ~24 (VGPR cap 64 from launch_bounds).
__device__ __forceinline__ float nk_dot(const __half* __restrict__ wrow,
                                        const float* __restrict__ xr) {
    float acc = 0.0f;
    #pragma unroll
    for (int h = 0; h < 2; ++h) {
        #pragma unroll
        for (int j = h * 6; j < h * 6 + 6; ++j) {
            float4 raw = *(const float4*)(wrow + 8 * j);   // 8 halves
            const __half2* hp = (const __half2*)&raw;
            float2 c0 = __half22float2(hp[0]);
            float2 c1 = __half22float2(hp[1]);
            float2 c2 = __half22float2(hp[2]);
            float2 c3 = __half22float2(hp[3]);
            float4 xv0 = *(const float4*)(xr + 8 * j);
            float4 xv1 = *(const float4*)(xr + 8 * j + 4);
            acc = fmaf(c0.x, xv0.x, acc); acc = fmaf(c0.y, xv0.y, acc);
            acc = fmaf(c1.x, xv0.z, acc); acc = fmaf(c1.y, xv0.w, acc);
            acc = fmaf(c2.x, xv1.x, acc); acc = fmaf(c2.y, xv1.y, acc);
            acc = fmaf(c3.x, xv1.z, acc); acc = fmaf(c3.y, xv1.w, acc);
        }
    }
    return acc;
}

__device__ __forceinline__ void stage_W(__half* __restrict__ wh,
                                        const __half* __restrict__ Wg,
                                        int tid) {
    for (int cidx = tid; cidx < NE / 8; cidx += NT_MAIN) {   // 1152 chunks
        const int i = cidx / 12;
        const int j = (cidx % 12) * 8;
        *(float4*)(wh + i * HPAD + j) = *(const float4*)(Wg + cidx * 8);
    }
}

// ---------------- Kernel 2: main fused pipeline, W from global ----------------
__global__ void __launch_bounds__(NT_MAIN, 8)
hier_main(const float* __restrict__ seq,  const float* __restrict__ M1,
          const float* __restrict__ Wres1, const float* __restrict__ g1,
          const float* __restrict__ b1,   const float* __restrict__ M2,
          const float* __restrict__ g2,   const float* __restrict__ b2,
          const __half* __restrict__ W1g, const __half* __restrict__ W2g,
          float* __restrict__ out) {
    __shared__ __align__(16) __half wh [D_OUT * HPAD];   // 19968 B
    __shared__ __align__(16) float xin[B_SZ * XPAD];
    __shared__ __align__(16) float xn [B_SZ * SPAD];
    __shared__ __align__(16) float x1b[B_SZ * SPAD];

    const int s   = blockIdx.x;
    const int tid = threadIdx.x;

    // xin: exactly one element per thread (8*64 = 512)
    {
        int b = tid >> 6, k = tid & 63;
        xin[b * XPAD + k] = seq[(b * S_LEN + s) * D_IN + k];
    }
    stage_W(wh, W1g + (size_t)s * NE, tid);
    __syncthreads();   // B1

    // Layer 1 GEMV: xt1 = x @ M1^T, residual = x @ Wres1^T  (768 items)
    for (int idx = tid; idx < B_SZ * D_OUT; idx += NT_MAIN) {
        int i = idx >> 3, b = idx & 7;
        const float4* m  = (const float4*)(M1 + i * D_IN);
        const float4* wr = (const float4*)(Wres1 + i * D_IN);
        const float*  xr = xin + b * XPAD;
        float at = 0.0f, ar = 0.0f;
        #pragma unroll
        for (int k = 0; k < D_IN / 4; ++k) {
            float4 mv = m[k], rv = wr[k];
            float x0 = xr[4*k], x1 = xr[4*k+1], x2 = xr[4*k+2], x3 = xr[4*k+3];
            at = fmaf(mv.x, x0, fmaf(mv.y, x1, fmaf(mv.z, x2, fmaf(mv.w, x3, at))));
            ar = fmaf(rv.x, x0, fmaf(rv.y, x1, fmaf(rv.z, x2, fmaf(rv.w, x3, ar))));
        }
        xn [b * SPAD + i] = at;
        x1b[b * SPAD + i] = ar;
    }
    __syncthreads();   // B2

    block_layernorm_w64(xn, g1, b1, tid);
    __syncthreads();   // B3

    // Nk1 + residual -> x1b   (pure LDS)
    for (int idx = tid; idx < B_SZ * D_OUT; idx += NT_MAIN) {
        int i = idx >> 3, b = idx & 7;
        x1b[b * SPAD + i] += nk_dot(wh + i * HPAD, xn + b * SPAD);
    }
    __syncthreads();   // B4

    stage_W(wh, W2g + (size_t)s * NE, tid);   // W2[s]; drain covered by 32 waves/CU

    // Layer 2 GEMV (wh not read here; B5 covers the wh writes)
    for (int idx = tid; idx < B_SZ * D_OUT; idx += NT_MAIN) {
        int i = idx >> 3, b = idx & 7;
        const float4* m  = (const float4*)(M2 + i * D_OUT);
        const float*  xr = x1b + b * SPAD;
        float at = 0.0f;
        #pragma unroll
        for (int k = 0; k < D_OUT / 4; ++k) {
            float4 mv = m[k];
            at = fmaf(mv.x, xr[4*k], fmaf(mv.y, xr[4*k+1],
                 fmaf(mv.z, xr[4*k+2], fmaf(mv.w, xr[4*k+3], at))));
        }
        xn[b * SPAD + i] = at;
    }
    __syncthreads();   // B5

    block_layernorm_w64(xn, g2, b2, tid);
    __syncthreads();   // B6

    for (int idx = tid; idx < B_SZ * D_OUT; idx += NT_MAIN) {
        int i = idx >> 3, b = idx & 7;
        float acc = nk_dot(wh + i * HPAD, xn + b * SPAD);
        out[(b * S_LEN + s) * D_OUT + i] = acc + x1b[b * SPAD + i];
    }
}

// ---------------- Fallback (round-1 proven kernel) if ws too small ----------------
__global__ void __launch_bounds__(NT_W)
hier_fallback(const float* __restrict__ seq,  const float* __restrict__ M1,
              const float* __restrict__ P1,   const float* __restrict__ Wres1,
              const float* __restrict__ g1,   const float* __restrict__ b1,
              const float* __restrict__ M2,   const float* __restrict__ P2,
              const float* __restrict__ g2,   const float* __restrict__ b2,
              float* __restrict__ out) {
    __shared__ __align__(16) float w[D_OUT * SPAD];
    __shared__ __align__(16) float xin[B_SZ * XPAD];
    __shared__ __align__(16) float xn [B_SZ * SPAD];
    __shared__ __align__(16) float x1b[B_SZ * SPAD];
    const int s = blockIdx.x, tid = threadIdx.x;
    const float sf = (float)s;

    for (int idx = tid; idx < B_SZ * D_IN; idx += NT_W) {
        int b = idx >> 6, k = idx & (D_IN - 1);
        xin[b * XPAD + k] = seq[(b * S_LEN + s) * D_IN + k];
    }
    for (int e = tid; e < NE; e += NT_W) {
        float pl[8];
        *(float4*)&pl[0] = *(const float4*)(P1 + e * NB);
        *(float4*)&pl[4] = *(const float4*)(P1 + e * NB + 4);
        float acc = 0.0f;
        #pragma unroll
        for (int g = 0; g < NB; ++g) {
            float v = sf * __builtin_amdgcn_rcpf((float)(e * NB + 2 + g));
            acc = fmaf(pl[g], cos_rev(v), acc);
        }
        int i = e / D_OUT;
        w[e + (SPAD - D_OUT) * i] = acc;
    }
    __syncthreads();
    for (int idx = tid; idx < B_SZ * D_OUT; idx += NT_W) {
        int i = idx >> 3, b = idx & 7;
        const float4* m  = (const float4*)(M1 + i * D_IN);
        const float4* wr = (const float4*)(Wres1 + i * D_IN);
        const float*  xr = xin + b * XPAD;
        float at = 0.0f, ar = 0.0f;
        #pragma unroll
        for (int k = 0; k < D_IN / 4; ++k) {
            float4 mv = m[k], rv = wr[k];
            float x0 = xr[4*k], x1 = xr[4*k+1], x2 = xr[4*k+2], x3 = xr[4*k+3];
            at = fmaf(mv.x, x0, fmaf(mv.y, x1, fmaf(mv.z, x2, fmaf(mv.w, x3, at))));
            ar = fmaf(rv.x, x0, fmaf(rv.y, x1, fmaf(rv.z, x2, fmaf(rv.w, x3, ar))));
        }
        xn [b * SPAD + i] = at;
        x1b[b * SPAD + i] = ar;
    }
    __syncthreads();
    {
        const int b = tid >> 5, r = tid & 31;
        float* row = xn + b * SPAD;
        float v0 = row[r], v1 = row[r + 32], v2 = row[r + 64];
        float sum = v0 + v1 + v2, sq = fmaf(v0, v0, fmaf(v1, v1, v2 * v2));
        #pragma unroll
        for (int off = 16; off > 0; off >>= 1) {
            sum += __shfl_down(sum, off, 32);
            sq  += __shfl_down(sq,  off, 32);
        }
        sum = __shfl(sum, 0, 32); sq = __shfl(sq, 0, 32);
        float mu = sum * (1.0f/96.0f), var = fmaf(sq, 1.0f/96.0f, -(mu*mu));
        float rs = rsqrtf(var + 1e-5f);
        row[r]      = fmaf((v0 - mu) * rs, g1[r],      b1[r]);
        row[r + 32] = fmaf((v1 - mu) * rs, g1[r + 32], b1[r + 32]);
        row[r + 64] = fmaf((v2 - mu) * rs, g1[r + 64], b1[r + 64]);
    }
    __syncthreads();
    for (int idx = tid; idx < B_SZ * D_OUT; idx += NT_W) {
        int i = idx >> 3, b = idx & 7;
        const float* wrow = w + i * SPAD;
        const float* xr   = xn + b * SPAD;
        float acc = 0.0f;
        #pragma unroll
        for (int j = 0; j < D_OUT / 4; ++j) {
            float4 wv = *(const float4*)(wrow + 4 * j);
            float4 xv = *(const float4*)(xr + 4 * j);
            acc = fmaf(wv.x, xv.x, fmaf(wv.y, xv.y, fmaf(wv.z, xv.z, fmaf(wv.w, xv.w, acc))));
        }
        x1b[b * SPAD + i] += acc;
    }
    __syncthreads();
    for (int e = tid; e < NE; e += NT_W) {
        float pl[8];
        *(float4*)&pl[0] = *(const float4*)(P2 + e * NB);
        *(float4*)&pl[4] = *(const float4*)(P2 + e * NB + 4);
        float acc = 0.0f;
        #pragma unroll
        for (int g = 0; g < NB; ++g) {
            float v = sf * __builtin_amdgcn_rcpf((float)(e * NB + 2 + g));
            acc = fmaf(pl[g], cos_rev(v), acc);
        }
        int i = e / D_OUT;
        w[e + (SPAD - D_OUT) * i] = acc;
    }
    for (int idx = tid; idx < B_SZ * D_OUT; idx += NT_W) {
        int i = idx >> 3, b = idx & 7;
        const float4* m  = (const float4*)(M2 + i * D_OUT);
        const float*  xr = x1b + b * SPAD;
        float at = 0.0f;
        #pragma unroll
        for (int k = 0; k < D_OUT / 4; ++k) {
            float4 mv = m[k];
            at = fmaf(mv.x, xr[4*k], fmaf(mv.y, xr[4*k+1],
                 fmaf(mv.z, xr[4*k+2], fmaf(mv.w, xr[4*k+3], at))));
        }
        xn[b * SPAD + i] = at;
    }
    __syncthreads();
    {
        const int b = tid >> 5, r = tid & 31;
        float* row = xn + b * SPAD;
        float v0 = row[r], v1 = row[r + 32], v2 = row[r + 64];
        float sum = v0 + v1 + v2, sq = fmaf(v0, v0, fmaf(v1, v1, v2 * v2));
        #pragma unroll
        for (int off = 16; off > 0; off >>= 1) {
            sum += __shfl_down(sum, off, 32);
            sq  += __shfl_down(sq,  off, 32);
        }
        sum = __shfl(sum, 0, 32); sq = __shfl(sq, 0, 32);
        float mu = sum * (1.0f/96.0f), var = fmaf(sq, 1.0f/96.0f, -(mu*mu));
        float rs = rsqrtf(var + 1e-5f);
        row[r]      = fmaf((v0 - mu) * rs, g2[r],      b2[r]);
        row[r + 32] = fmaf((v1 - mu) * rs, g2[r + 32], b2[r + 32]);
        row[r + 64] = fmaf((v2 - mu) * rs, g2[r + 64], b2[r + 64]);
    }
    __syncthreads();
    for (int idx = tid; idx < B_SZ * D_OUT; idx += NT_W) {
        int i = idx >> 3, b = idx & 7;
        const float* wrow = w + i * SPAD;
        const float* xr   = xn + b * SPAD;
        float acc = 0.0f;
        #pragma unroll
        for (int j = 0; j < D_OUT / 4; ++j) {
            float4 wv = *(const float4*)(wrow + 4 * j);
            float4 xv = *(const float4*)(xr + 4 * j);
            acc = fmaf(wv.x, xv.x, fmaf(wv.y, xv.y, fmaf(wv.z, xv.z, fmaf(wv.w, xv.w, acc))));
        }
        out[(b * S_LEN + s) * D_OUT + i] = acc + x1b[b * SPAD + i];
    }
}

extern "C" void kernel_launch(void* const* d_in, const int* in_sizes, int n_in,
                              void* d_out, int out_size, void* d_ws, size_t ws_size,
                              hipStream_t stream) {
    const float* seq   = (const float*)d_in[0];
    const float* M1    = (const float*)d_in[1];
    const float* P1    = (const float*)d_in[2];
    const float* Wres1 = (const float*)d_in[3];
    const float* g1    = (const float*)d_in[4];
    const float* b1    = (const float*)d_in[5];
    const float* M2    = (const float*)d_in[6];
    const float* P2    = (const float*)d_in[7];
    const float* g2    = (const float*)d_in[8];
    const float* b2    = (const float*)d_in[9];
    float* out = (float*)d_out;

    const size_t need = (size_t)2 * S_LEN * NE * sizeof(__half);   // 37.75 MB
    if (ws_size >= need) {
        __half* W1 = (__half*)d_ws;
        __half* W2 = W1 + (size_t)S_LEN * NE;
        w_kernel<<<dim3(NCHUNK * (NE / NT_W)), dim3(NT_W), 0, stream>>>(P1, P2, W1, W2);
        hier_main<<<dim3(S_LEN), dim3(NT_MAIN), 0, stream>>>(
            seq, M1, Wres1, g1, b1, M2, g2, b2, W1, W2, out);
    } else {
        hier_fallback<<<dim3(S_LEN), dim3(NT_W), 0, stream>>>(
            seq, M1, P1, Wres1, g1, b1, M2, P2, g2, b2, out);
    }
}

// Round 6
// 125.328 us; speedup vs baseline: 1.9303x; 1.9303x over previous
//
#include <hip/hip_runtime.h>
#include <hip/hip_fp16.h>

#define S_LEN    1024
#define B_SZ     8
#define D_IN     64
#define D_OUT    96
#define NB       8
#define NE       (D_OUT * D_OUT)     // 9216 elements per layer
#define CHUNK    8                   // s-steps per recurrence chain
#define NCHUNK   (S_LEN / CHUNK)     // 128 -> 4608 blocks = 18/CU exactly
#define SPAD     100                 // padded row stride (floats), 96-wide rows
#define XPAD     68                  // padded row stride (floats), 64-wide rows
#define HPAD     104                 // padded row stride (halves) for W tile
#define NT_MAIN  512                 // 8 waves/block
#define NT_W     256

__device__ __forceinline__ float cos_rev(float v) {   // cos(2*pi*v), v in revolutions
    v -= floorf(v);
    return __builtin_amdgcn_cosf(v);
}

// ---------------- Kernel 1: materialize W1, W2 (f16) for all s ----------------
// c(s+1) = 2cos(2pi/p)*c(s) - c(s-1). One thread owns one element e (8 chains).
__global__ void __launch_bounds__(NT_W)
w_kernel(const float* __restrict__ P1, const float* __restrict__ P2,
         __half* __restrict__ W1, __half* __restrict__ W2) {
    const int c  = blockIdx.x / (NE / NT_W);
    const int eb = blockIdx.x % (NE / NT_W);
    const int e  = eb * NT_W + threadIdx.x;
    const int s0 = c * CHUNK;
    const float s0f = (float)s0;

    float p1l[NB], p2l[NB];
    *(float4*)&p1l[0] = *(const float4*)(P1 + e * NB);
    *(float4*)&p1l[4] = *(const float4*)(P1 + e * NB + 4);
    *(float4*)&p2l[0] = *(const float4*)(P2 + e * NB);
    *(float4*)&p2l[4] = *(const float4*)(P2 + e * NB + 4);

    float cc[NB], cp[NB], kk[NB];
    #pragma unroll
    for (int g = 0; g < NB; ++g) {
        const float inv = __builtin_amdgcn_rcpf((float)(e * NB + 2 + g));
        cc[g] = cos_rev(s0f * inv);            // c(s0)
        cp[g] = cos_rev((s0f - 1.0f) * inv);   // c(s0-1); cos even, s0=0 fine
        kk[g] = 2.0f * __builtin_amdgcn_cosf(inv);  // 2cos(2pi/p), inv <= 0.5
    }

    #pragma unroll
    for (int s = s0; s < s0 + CHUNK; ++s) {
        float a1 = 0.0f, a2 = 0.0f;
        #pragma unroll
        for (int g = 0; g < NB; ++g) {
            a1 = fmaf(p1l[g], cc[g], a1);
            a2 = fmaf(p2l[g], cc[g], a2);
        }
        W1[s * NE + e] = __float2half(a1);   // lanes consecutive e -> coalesced
        W2[s * NE + e] = __float2half(a2);
        #pragma unroll
        for (int g = 0; g < NB; ++g) {
            float cn = fmaf(kk[g], cc[g], -cp[g]);
            cp[g] = cc[g];
            cc[g] = cn;
        }
    }
}

// ---------------- helpers for the 512-thread main kernel ----------------
// LayerNorm, one wave64 per batch row (8 waves = 8 rows).
__device__ __forceinline__ void block_layernorm_w64(float* __restrict__ buf,
                                                    const float* __restrict__ gamma,
                                                    const float* __restrict__ beta,
                                                    int tid) {
    const int b    = tid >> 6;
    const int lane = tid & 63;
    float* row = buf + b * SPAD;
    const bool hi = (lane < 32);
    float v0 = row[lane];
    float v1 = hi ? row[lane + 64] : 0.0f;
    float sum = v0 + v1;
    float sq  = fmaf(v0, v0, v1 * v1);
    #pragma unroll
    for (int off = 32; off > 0; off >>= 1) {
        sum += __shfl_down(sum, off, 64);
        sq  += __shfl_down(sq,  off, 64);
    }
    sum = __shfl(sum, 0, 64);
    sq  = __shfl(sq,  0, 64);
    const float mu  = sum * (1.0f / 96.0f);
    const float var = fmaf(sq, 1.0f / 96.0f, -(mu * mu));
    const float rs  = rsqrtf(var + 1e-5f);
    row[lane] = fmaf((v0 - mu) * rs, gamma[lane], beta[lane]);
    if (hi)
        row[lane + 64] = fmaf((v1 - mu) * rs, gamma[lane + 64], beta[lane + 64]);
}

// acc = sum_j xr[j] * wrow[j], W f16 in LDS.
__device__ __forceinline__ float nk_dot(const __half* __restrict__ wrow,
                                        const float* __restrict__ xr) {
    float acc = 0.0f;
    #pragma unroll
    for (int h = 0; h < 2; ++h) {
        #pragma unroll
        for (int j = h * 6; j < h * 6 + 6; ++j) {
            float4 raw = *(const float4*)(wrow + 8 * j);   // 8 halves
            const __half2* hp = (const __half2*)&raw;
            float2 c0 = __half22float2(hp[0]);
            float2 c1 = __half22float2(hp[1]);
            float2 c2 = __half22float2(hp[2]);
            float2 c3 = __half22float2(hp[3]);
            float4 xv0 = *(const float4*)(xr + 8 * j);
            float4 xv1 = *(const float4*)(xr + 8 * j + 4);
            acc = fmaf(c0.x, xv0.x, acc); acc = fmaf(c0.y, xv0.y, acc);
            acc = fmaf(c1.x, xv0.z, acc); acc = fmaf(c1.y, xv0.w, acc);
            acc = fmaf(c2.x, xv1.x, acc); acc = fmaf(c2.y, xv1.y, acc);
            acc = fmaf(c3.x, xv1.z, acc); acc = fmaf(c3.y, xv1.w, acc);
        }
    }
    return acc;
}

__device__ __forceinline__ void stage_W(__half* __restrict__ wh,
                                        const __half* __restrict__ Wg,
                                        int tid) {
    for (int cidx = tid; cidx < NE / 8; cidx += NT_MAIN) {   // 1152 chunks
        const int i = cidx / 12;
        const int j = (cidx % 12) * 8;
        *(float4*)(wh + i * HPAD + j) = *(const float4*)(Wg + cidx * 8);
    }
}

// ---------------- Kernel 2: main fused pipeline, W from global ----------------
// launch_bounds min-waves 4 (NOT 8): round 5's (512,8) forced VGPR to 32 and
// spilled (FETCH 274 MB / WRITE 368 MB scratch traffic). Cap 128, expect ~84.
__global__ void __launch_bounds__(NT_MAIN, 4)
hier_main(const float* __restrict__ seq,  const float* __restrict__ M1,
          const float* __restrict__ Wres1, const float* __restrict__ g1,
          const float* __restrict__ b1,   const float* __restrict__ M2,
          const float* __restrict__ g2,   const float* __restrict__ b2,
          const __half* __restrict__ W1g, const __half* __restrict__ W2g,
          float* __restrict__ out) {
    __shared__ __align__(16) __half wh [D_OUT * HPAD];   // 19968 B
    __shared__ __align__(16) float xin[B_SZ * XPAD];
    __shared__ __align__(16) float xn [B_SZ * SPAD];
    __shared__ __align__(16) float x1b[B_SZ * SPAD];

    const int s   = blockIdx.x;
    const int tid = threadIdx.x;

    // xin: exactly one element per thread (8*64 = 512)
    {
        int b = tid >> 6, k = tid & 63;
        xin[b * XPAD + k] = seq[(b * S_LEN + s) * D_IN + k];
    }
    stage_W(wh, W1g + (size_t)s * NE, tid);
    __syncthreads();   // B1

    // Layer 1 GEMV: xt1 = x @ M1^T, residual = x @ Wres1^T  (768 items)
    for (int idx = tid; idx < B_SZ * D_OUT; idx += NT_MAIN) {
        int i = idx >> 3, b = idx & 7;
        const float4* m  = (const float4*)(M1 + i * D_IN);
        const float4* wr = (const float4*)(Wres1 + i * D_IN);
        const float*  xr = xin + b * XPAD;
        float at = 0.0f, ar = 0.0f;
        #pragma unroll
        for (int k = 0; k < D_IN / 4; ++k) {
            float4 mv = m[k], rv = wr[k];
            float x0 = xr[4*k], x1 = xr[4*k+1], x2 = xr[4*k+2], x3 = xr[4*k+3];
            at = fmaf(mv.x, x0, fmaf(mv.y, x1, fmaf(mv.z, x2, fmaf(mv.w, x3, at))));
            ar = fmaf(rv.x, x0, fmaf(rv.y, x1, fmaf(rv.z, x2, fmaf(rv.w, x3, ar))));
        }
        xn [b * SPAD + i] = at;
        x1b[b * SPAD + i] = ar;
    }
    __syncthreads();   // B2

    block_layernorm_w64(xn, g1, b1, tid);
    __syncthreads();   // B3

    // Nk1 + residual -> x1b   (pure LDS)
    for (int idx = tid; idx < B_SZ * D_OUT; idx += NT_MAIN) {
        int i = idx >> 3, b = idx & 7;
        x1b[b * SPAD + i] += nk_dot(wh + i * HPAD, xn + b * SPAD);
    }
    __syncthreads();   // B4

    stage_W(wh, W2g + (size_t)s * NE, tid);   // W2[s]; drain hidden by occupancy

    // Layer 2 GEMV (wh not read here; B5 covers the wh writes)
    for (int idx = tid; idx < B_SZ * D_OUT; idx += NT_MAIN) {
        int i = idx >> 3, b = idx & 7;
        const float4* m  = (const float4*)(M2 + i * D_OUT);
        const float*  xr = x1b + b * SPAD;
        float at = 0.0f;
        #pragma unroll
        for (int k = 0; k < D_OUT / 4; ++k) {
            float4 mv = m[k];
            at = fmaf(mv.x, xr[4*k], fmaf(mv.y, xr[4*k+1],
                 fmaf(mv.z, xr[4*k+2], fmaf(mv.w, xr[4*k+3], at))));
        }
        xn[b * SPAD + i] = at;
    }
    __syncthreads();   // B5

    block_layernorm_w64(xn, g2, b2, tid);
    __syncthreads();   // B6

    for (int idx = tid; idx < B_SZ * D_OUT; idx += NT_MAIN) {
        int i = idx >> 3, b = idx & 7;
        float acc = nk_dot(wh + i * HPAD, xn + b * SPAD);
        out[(b * S_LEN + s) * D_OUT + i] = acc + x1b[b * SPAD + i];
    }
}

// ---------------- Fallback (round-1 proven kernel) if ws too small ----------------
__global__ void __launch_bounds__(NT_W)
hier_fallback(const float* __restrict__ seq,  const float* __restrict__ M1,
              const float* __restrict__ P1,   const float* __restrict__ Wres1,
              const float* __restrict__ g1,   const float* __restrict__ b1,
              const float* __restrict__ M2,   const float* __restrict__ P2,
              const float* __restrict__ g2,   const float* __restrict__ b2,
              float* __restrict__ out) {
    __shared__ __align__(16) float w[D_OUT * SPAD];
    __shared__ __align__(16) float xin[B_SZ * XPAD];
    __shared__ __align__(16) float xn [B_SZ * SPAD];
    __shared__ __align__(16) float x1b[B_SZ * SPAD];
    const int s = blockIdx.x, tid = threadIdx.x;
    const float sf = (float)s;

    for (int idx = tid; idx < B_SZ * D_IN; idx += NT_W) {
        int b = idx >> 6, k = idx & (D_IN - 1);
        xin[b * XPAD + k] = seq[(b * S_LEN + s) * D_IN + k];
    }
    for (int e = tid; e < NE; e += NT_W) {
        float pl[8];
        *(float4*)&pl[0] = *(const float4*)(P1 + e * NB);
        *(float4*)&pl[4] = *(const float4*)(P1 + e * NB + 4);
        float acc = 0.0f;
        #pragma unroll
        for (int g = 0; g < NB; ++g) {
            float v = sf * __builtin_amdgcn_rcpf((float)(e * NB + 2 + g));
            acc = fmaf(pl[g], cos_rev(v), acc);
        }
        int i = e / D_OUT;
        w[e + (SPAD - D_OUT) * i] = acc;
    }
    __syncthreads();
    for (int idx = tid; idx < B_SZ * D_OUT; idx += NT_W) {
        int i = idx >> 3, b = idx & 7;
        const float4* m  = (const float4*)(M1 + i * D_IN);
        const float4* wr = (const float4*)(Wres1 + i * D_IN);
        const float*  xr = xin + b * XPAD;
        float at = 0.0f, ar = 0.0f;
        #pragma unroll
        for (int k = 0; k < D_IN / 4; ++k) {
            float4 mv = m[k], rv = wr[k];
            float x0 = xr[4*k], x1 = xr[4*k+1], x2 = xr[4*k+2], x3 = xr[4*k+3];
            at = fmaf(mv.x, x0, fmaf(mv.y, x1, fmaf(mv.z, x2, fmaf(mv.w, x3, at))));
            ar = fmaf(rv.x, x0, fmaf(rv.y, x1, fmaf(rv.z, x2, fmaf(rv.w, x3, ar))));
        }
        xn [b * SPAD + i] = at;
        x1b[b * SPAD + i] = ar;
    }
    __syncthreads();
    {
        const int b = tid >> 5, r = tid & 31;
        float* row = xn + b * SPAD;
        float v0 = row[r], v1 = row[r + 32], v2 = row[r + 64];
        float sum = v0 + v1 + v2, sq = fmaf(v0, v0, fmaf(v1, v1, v2 * v2));
        #pragma unroll
        for (int off = 16; off > 0; off >>= 1) {
            sum += __shfl_down(sum, off, 32);
            sq  += __shfl_down(sq,  off, 32);
        }
        sum = __shfl(sum, 0, 32); sq = __shfl(sq, 0, 32);
        float mu = sum * (1.0f/96.0f), var = fmaf(sq, 1.0f/96.0f, -(mu*mu));
        float rs = rsqrtf(var + 1e-5f);
        row[r]      = fmaf((v0 - mu) * rs, g1[r],      b1[r]);
        row[r + 32] = fmaf((v1 - mu) * rs, g1[r + 32], b1[r + 32]);
        row[r + 64] = fmaf((v2 - mu) * rs, g1[r + 64], b1[r + 64]);
    }
    __syncthreads();
    for (int idx = tid; idx < B_SZ * D_OUT; idx += NT_W) {
        int i = idx >> 3, b = idx & 7;
        const float* wrow = w + i * SPAD;
        const float* xr   = xn + b * SPAD;
        float acc = 0.0f;
        #pragma unroll
        for (int j = 0; j < D_OUT / 4; ++j) {
            float4 wv = *(const float4*)(wrow + 4 * j);
            float4 xv = *(const float4*)(xr + 4 * j);
            acc = fmaf(wv.x, xv.x, fmaf(wv.y, xv.y, fmaf(wv.z, xv.z, fmaf(wv.w, xv.w, acc))));
        }
        x1b[b * SPAD + i] += acc;
    }
    __syncthreads();
    for (int e = tid; e < NE; e += NT_W) {
        float pl[8];
        *(float4*)&pl[0] = *(const float4*)(P2 + e * NB);
        *(float4*)&pl[4] = *(const float4*)(P2 + e * NB + 4);
        float acc = 0.0f;
        #pragma unroll
        for (int g = 0; g < NB; ++g) {
            float v = sf * __builtin_amdgcn_rcpf((float)(e * NB + 2 + g));
            acc = fmaf(pl[g], cos_rev(v), acc);
        }
        int i = e / D_OUT;
        w[e + (SPAD - D_OUT) * i] = acc;
    }
    for (int idx = tid; idx < B_SZ * D_OUT; idx += NT_W) {
        int i = idx >> 3, b = idx & 7;
        const float4* m  = (const float4*)(M2 + i * D_OUT);
        const float*  xr = x1b + b * SPAD;
        float at = 0.0f;
        #pragma unroll
        for (int k = 0; k < D_OUT / 4; ++k) {
            float4 mv = m[k];
            at = fmaf(mv.x, xr[4*k], fmaf(mv.y, xr[4*k+1],
                 fmaf(mv.z, xr[4*k+2], fmaf(mv.w, xr[4*k+3], at))));
        }
        xn[b * SPAD + i] = at;
    }
    __syncthreads();
    {
        const int b = tid >> 5, r = tid & 31;
        float* row = xn + b * SPAD;
        float v0 = row[r], v1 = row[r + 32], v2 = row[r + 64];
        float sum = v0 + v1 + v2, sq = fmaf(v0, v0, fmaf(v1, v1, v2 * v2));
        #pragma unroll
        for (int off = 16; off > 0; off >>= 1) {
            sum += __shfl_down(sum, off, 32);
            sq  += __shfl_down(sq,  off, 32);
        }
        sum = __shfl(sum, 0, 32); sq = __shfl(sq, 0, 32);
        float mu = sum * (1.0f/96.0f), var = fmaf(sq, 1.0f/96.0f, -(mu*mu));
        float rs = rsqrtf(var + 1e-5f);
        row[r]      = fmaf((v0 - mu) * rs, g2[r],      b2[r]);
        row[r + 32] = fmaf((v1 - mu) * rs, g2[r + 32], b2[r + 32]);
        row[r + 64] = fmaf((v2 - mu) * rs, g2[r + 64], b2[r + 64]);
    }
    __syncthreads();
    for (int idx = tid; idx < B_SZ * D_OUT; idx += NT_W) {
        int i = idx >> 3, b = idx & 7;
        const float* wrow = w + i * SPAD;
        const float* xr   = xn + b * SPAD;
        float acc = 0.0f;
        #pragma unroll
        for (int j = 0; j < D_OUT / 4; ++j) {
            float4 wv = *(const float4*)(wrow + 4 * j);
            float4 xv = *(const float4*)(xr + 4 * j);
            acc = fmaf(wv.x, xv.x, fmaf(wv.y, xv.y, fmaf(wv.z, xv.z, fmaf(wv.w, xv.w, acc))));
        }
        out[(b * S_LEN + s) * D_OUT + i] = acc + x1b[b * SPAD + i];
    }
}

extern "C" void kernel_launch(void* const* d_in, const int* in_sizes, int n_in,
                              void* d_out, int out_size, void* d_ws, size_t ws_size,
                              hipStream_t stream) {
    const float* seq   = (const float*)d_in[0];
    const float* M1    = (const float*)d_in[1];
    const float* P1    = (const float*)d_in[2];
    const float* Wres1 = (const float*)d_in[3];
    const float* g1    = (const float*)d_in[4];
    const float* b1    = (const float*)d_in[5];
    const float* M2    = (const float*)d_in[6];
    const float* P2    = (const float*)d_in[7];
    const float* g2    = (const float*)d_in[8];
    const float* b2    = (const float*)d_in[9];
    float* out = (float*)d_out;

    const size_t need = (size_t)2 * S_LEN * NE * sizeof(__half);   // 37.75 MB
    if (ws_size >= need) {
        __half* W1 = (__half*)d_ws;
        __half* W2 = W1 + (size_t)S_LEN * NE;
        w_kernel<<<dim3(NCHUNK * (NE / NT_W)), dim3(NT_W), 0, stream>>>(P1, P2, W1, W2);
        hier_main<<<dim3(S_LEN), dim3(NT_MAIN), 0, stream>>>(
            seq, M1, Wres1, g1, b1, M2, g2, b2, W1, W2, out);
    } else {
        hier_fallback<<<dim3(S_LEN), dim3(NT_W), 0, stream>>>(
            seq, M1, P1, Wres1, g1, b1, M2, P2, g2, b2, out);
    }
}